// Round 1
// baseline (3331.807 us; speedup 1.0000x reference)
//
#include <hip/hip_runtime.h>
#include <math.h>

#define NB   16
#define NPTS 4096
#define SS   1024
#define KK   64
#define CIN  64

// d2 computed to bit-match XLA: separate mul/add (no FMA contraction),
// sum order (dx^2 + dy^2) + dz^2.
__device__ __forceinline__ float dist2(float ax, float ay, float az,
                                       float bx, float by, float bz) {
#pragma clang fp contract(off)
  float dx = ax - bx, dy = ay - by, dz = az - bz;
  float a = dx * dx, b = dy * dy, c = dz * dz;
  return (a + b) + c;
}

// ---------------------------------------------------------------------------
// Kernel 1: farthest point sampling, one block per cloud.
// Exact reference semantics: start at point 0, S-1 iterations of
// argmax(dmin) (first-index tie-break) then dmin = min(dmin, d2(new)).
// Also writes pos_out (centers) and batch_out.
// ---------------------------------------------------------------------------
#define FPS_TPB 256
#define FPS_PPT (NPTS / FPS_TPB)  // 16 points per thread

__global__ __launch_bounds__(FPS_TPB) void fps_kernel(
    const float* __restrict__ pos, int* __restrict__ fps_idx,
    float* __restrict__ centers, float* __restrict__ out_pos,
    float* __restrict__ out_batch) {
  __shared__ float px[NPTS], py[NPTS], pz[NPTS];
  __shared__ float swv[2][4];
  __shared__ int   swi[2][4];

  const int b = blockIdx.x, t = threadIdx.x;
  const float* p = pos + (size_t)b * NPTS * 3;

  // stage positions (coalesced linear read, SoA in LDS)
  for (int j = t; j < NPTS * 3; j += FPS_TPB) {
    float v = p[j];
    int pt = j / 3, ch = j - pt * 3;
    if (ch == 0) px[pt] = v;
    else if (ch == 1) py[pt] = v;
    else pz[pt] = v;
  }
  for (int j = t; j < SS; j += FPS_TPB)
    out_batch[b * SS + j] = (float)b;
  __syncthreads();

  const int base = t * FPS_PPT;
  float x[FPS_PPT], y[FPS_PPT], z[FPS_PPT], dm[FPS_PPT];
  const float c0x = px[0], c0y = py[0], c0z = pz[0];
#pragma unroll
  for (int u = 0; u < FPS_PPT; ++u) {
    x[u] = px[base + u]; y[u] = py[base + u]; z[u] = pz[base + u];
    dm[u] = dist2(x[u], y[u], z[u], c0x, c0y, c0z);
  }
  if (t == 0) {
    int r = b * SS;
    fps_idx[r] = 0;
    centers[r * 3 + 0] = c0x; centers[r * 3 + 1] = c0y; centers[r * 3 + 2] = c0z;
    out_pos[r * 3 + 0] = c0x; out_pos[r * 3 + 1] = c0y; out_pos[r * 3 + 2] = c0z;
  }

  const int wid = t >> 6, lane = t & 63;
  int parity = 0;
  for (int s = 1; s < SS; ++s) {
    // local argmax (ascending index scan, strict > keeps first index)
    float bv = dm[0]; int bi = base;
#pragma unroll
    for (int u = 1; u < FPS_PPT; ++u)
      if (dm[u] > bv) { bv = dm[u]; bi = base + u; }
    // wave64 argmax reduce with first-index tie-break
#pragma unroll
    for (int off = 32; off > 0; off >>= 1) {
      float ov = __shfl_down(bv, off, 64);
      int   oi = __shfl_down(bi, off, 64);
      if (ov > bv || (ov == bv && oi < bi)) { bv = ov; bi = oi; }
    }
    if (lane == 0) { swv[parity][wid] = bv; swi[parity][wid] = bi; }
    __syncthreads();
    // every thread reduces the 4 wave results identically
    float gv = swv[parity][0]; int gi = swi[parity][0];
#pragma unroll
    for (int w = 1; w < 4; ++w) {
      float ov = swv[parity][w]; int oi = swi[parity][w];
      if (ov > gv || (ov == gv && oi < gi)) { gv = ov; gi = oi; }
    }
    const float cx = px[gi], cy = py[gi], cz = pz[gi];
#pragma unroll
    for (int u = 0; u < FPS_PPT; ++u) {
      float d2 = dist2(x[u], y[u], z[u], cx, cy, cz);
      dm[u] = fminf(dm[u], d2);
    }
    if (t == 0) {
      int r = b * SS + s;
      fps_idx[r] = gi;
      centers[r * 3 + 0] = cx; centers[r * 3 + 1] = cy; centers[r * 3 + 2] = cz;
      out_pos[r * 3 + 0] = cx; out_pos[r * 3 + 1] = cy; out_pos[r * 3 + 2] = cz;
    }
    parity ^= 1;
  }
}

// ---------------------------------------------------------------------------
// Kernel 2: ball query — exact K-smallest-d2-within-radius set, one block
// per center. Binary search on float-as-uint keys; ties at the Kth boundary
// resolved by lowest index (matches lax.top_k set membership).
// ---------------------------------------------------------------------------
__global__ __launch_bounds__(256) void ballq_kernel(
    const float* __restrict__ pos, const float* __restrict__ centers,
    int* __restrict__ nbr) {
  __shared__ float d2s[NPTS];
  __shared__ int scnt;
  __shared__ int sslot;

  const int c = blockIdx.x, t = threadIdx.x;
  const int b = c >> 10;
  const float R2 = 0.04f;  // f32(0.2**2 in double) — NOT 0.2f*0.2f (differs by 1 ulp)
  const unsigned KR2 = __float_as_uint(R2);

  const float cx = centers[c * 3 + 0], cy = centers[c * 3 + 1], cz = centers[c * 3 + 2];
  const float* p = pos + (size_t)b * NPTS * 3;

  int localv = 0;
  for (int i = t; i < NPTS; i += 256) {
    float ax = p[i * 3 + 0], ay = p[i * 3 + 1], az = p[i * 3 + 2];
    float d2 = dist2(cx, cy, cz, ax, ay, az);
    d2s[i] = d2;
    localv += (d2 <= R2) ? 1 : 0;
  }
  if (t == 0) scnt = 0;
  __syncthreads();
  atomicAdd(&scnt, localv);
  __syncthreads();
  const int nv = scnt;
  __syncthreads();

  if (nv <= KK) {
    if (t == 0) sslot = 0;
    __syncthreads();
    for (int i = t; i < NPTS; i += 256) {
      if (d2s[i] <= R2) {
        int ps = atomicAdd(&sslot, 1);
        nbr[(size_t)c * KK + ps] = b * NPTS + i;
      }
    }
    __syncthreads();
    for (int j = nv + t; j < KK; j += 256) nbr[(size_t)c * KK + j] = -1;
  } else {
    // binary search for the Kth smallest key u (keys are non-negative floats
    // viewed as uint -> monotone)
    unsigned lo = 0, hi = KR2;
    while (lo < hi) {
      unsigned mid = lo + ((hi - lo) >> 1);
      if (t == 0) scnt = 0;
      __syncthreads();
      int lc = 0;
      for (int i = t; i < NPTS; i += 256)
        lc += (__float_as_uint(d2s[i]) <= mid) ? 1 : 0;
      atomicAdd(&scnt, lc);
      __syncthreads();
      unsigned cle = (unsigned)scnt;
      __syncthreads();
      if (cle >= KK) hi = mid; else lo = mid + 1;
    }
    const unsigned u = lo;

    // c_less = #{key < u}
    if (t == 0) scnt = 0;
    __syncthreads();
    {
      int lc = 0;
      if (u > 0)
        for (int i = t; i < NPTS; i += 256)
          lc += (__float_as_uint(d2s[i]) < u) ? 1 : 0;
      atomicAdd(&scnt, lc);
    }
    __syncthreads();
    const int cless = scnt;
    __syncthreads();

    // c_le_u = #{key <= u}
    if (t == 0) scnt = 0;
    __syncthreads();
    {
      int lc = 0;
      for (int i = t; i < NPTS; i += 256)
        lc += (__float_as_uint(d2s[i]) <= u) ? 1 : 0;
      atomicAdd(&scnt, lc);
    }
    __syncthreads();
    const int cleu = scnt;
    __syncthreads();

    const int need = KK - cless;
    const bool allfit = (cleu <= KK);  // then cleu == KK exactly

    if (t == 0) sslot = 0;
    __syncthreads();
    for (int i = t; i < NPTS; i += 256) {
      unsigned k = __float_as_uint(d2s[i]);
      if (k < u) {
        int ps = atomicAdd(&sslot, 1);
        nbr[(size_t)c * KK + ps] = b * NPTS + i;
      } else if (k == u) {
        if (allfit) {
          int ps = atomicAdd(&sslot, 1);
          nbr[(size_t)c * KK + ps] = b * NPTS + i;
        } else {
          // rare: equal keys straddle the boundary -> take lowest indices
          int rank = 0;
          for (int j = 0; j < i; ++j)
            rank += (__float_as_uint(d2s[j]) == u) ? 1 : 0;
          if (rank < need) nbr[(size_t)c * KK + cless + rank] = b * NPTS + i;
        }
      }
    }
  }
}

// ---------------------------------------------------------------------------
// Kernel 3: gather + 3-layer MLP + masked max-pool, one block per center.
// fp32 vector-ALU, 4x4 register-blocked tiles; weights read from global
// (L1-resident: W1+W2+W3 = 66 KB total, shared by all 16384 blocks).
// ---------------------------------------------------------------------------
__global__ __launch_bounds__(256) void mlp_kernel(
    const float* __restrict__ x, const float* __restrict__ pos,
    const float* __restrict__ centers, const int* __restrict__ nbr,
    const float* __restrict__ W1, const float* __restrict__ b1,
    const float* __restrict__ W2, const float* __restrict__ b2,
    const float* __restrict__ W3, const float* __restrict__ b3,
    float* __restrict__ out) {
  __shared__ float feat[64][68];  // 67 used (64 ch + 3 rel), stride 68
  __shared__ float h1[64][68];
  __shared__ float h2[64][68];
  __shared__ float red[16][128];
  __shared__ int nbr_s[64];
  __shared__ int valid_s[64];

  const int c = blockIdx.x, t = threadIdx.x;

  if (t < 64) {
    int g = nbr[(size_t)c * KK + t];
    nbr_s[t] = g;
    valid_s[t] = (g >= 0) ? 1 : 0;
  }
  __syncthreads();

  // gather x features: row k = neighbor, 64 channels
  {
    const int ch = t & 63;
    for (int k = t >> 6; k < 64; k += 4) {
      int g = nbr_s[k];
      feat[k][ch] = (g >= 0) ? x[(size_t)g * CIN + ch] : 0.f;
    }
  }
  if (t < 64) {
    int g = nbr_s[t];
    float cx = centers[c * 3 + 0], cy = centers[c * 3 + 1], cz = centers[c * 3 + 2];
    if (g >= 0) {
      feat[t][64] = pos[(size_t)g * 3 + 0] - cx;
      feat[t][65] = pos[(size_t)g * 3 + 1] - cy;
      feat[t][66] = pos[(size_t)g * 3 + 2] - cz;
    } else {
      feat[t][64] = 0.f; feat[t][65] = 0.f; feat[t][66] = 0.f;
    }
    feat[t][67] = 0.f;
  }
  __syncthreads();

  const int tr = t >> 4, tc = t & 15;
  const int k0 = tr * 4;

  // Layer 1: relu(feat[64x67] @ W1[67x64] + b1) -> h1
  {
    const int j0 = tc * 4;
    float acc[4][4];
    const float4 bb = *(const float4*)(b1 + j0);
#pragma unroll
    for (int r = 0; r < 4; ++r) {
      acc[r][0] = bb.x; acc[r][1] = bb.y; acc[r][2] = bb.z; acc[r][3] = bb.w;
    }
    for (int i = 0; i < 67; ++i) {
      float fa[4];
#pragma unroll
      for (int r = 0; r < 4; ++r) fa[r] = feat[k0 + r][i];
      const float4 wb = *(const float4*)(W1 + i * 64 + j0);
#pragma unroll
      for (int r = 0; r < 4; ++r) {
        acc[r][0] += fa[r] * wb.x; acc[r][1] += fa[r] * wb.y;
        acc[r][2] += fa[r] * wb.z; acc[r][3] += fa[r] * wb.w;
      }
    }
#pragma unroll
    for (int r = 0; r < 4; ++r) {
      float4 v;
      v.x = fmaxf(acc[r][0], 0.f); v.y = fmaxf(acc[r][1], 0.f);
      v.z = fmaxf(acc[r][2], 0.f); v.w = fmaxf(acc[r][3], 0.f);
      *(float4*)(&h1[k0 + r][j0]) = v;
    }
  }
  __syncthreads();

  // Layer 2: relu(h1[64x64] @ W2[64x64] + b2) -> h2
  {
    const int j0 = tc * 4;
    float acc[4][4];
    const float4 bb = *(const float4*)(b2 + j0);
#pragma unroll
    for (int r = 0; r < 4; ++r) {
      acc[r][0] = bb.x; acc[r][1] = bb.y; acc[r][2] = bb.z; acc[r][3] = bb.w;
    }
    for (int i = 0; i < 64; ++i) {
      float fa[4];
#pragma unroll
      for (int r = 0; r < 4; ++r) fa[r] = h1[k0 + r][i];
      const float4 wb = *(const float4*)(W2 + i * 64 + j0);
#pragma unroll
      for (int r = 0; r < 4; ++r) {
        acc[r][0] += fa[r] * wb.x; acc[r][1] += fa[r] * wb.y;
        acc[r][2] += fa[r] * wb.z; acc[r][3] += fa[r] * wb.w;
      }
    }
#pragma unroll
    for (int r = 0; r < 4; ++r) {
      float4 v;
      v.x = fmaxf(acc[r][0], 0.f); v.y = fmaxf(acc[r][1], 0.f);
      v.z = fmaxf(acc[r][2], 0.f); v.w = fmaxf(acc[r][3], 0.f);
      *(float4*)(&h2[k0 + r][j0]) = v;
    }
  }
  __syncthreads();

  // Layer 3: h2[64x64] @ W3[64x128] + b3, masked max over k
  {
    const int j0 = tc * 8;
    float acc[4][8];
    const float4 bb0 = *(const float4*)(b3 + j0);
    const float4 bb1 = *(const float4*)(b3 + j0 + 4);
#pragma unroll
    for (int r = 0; r < 4; ++r) {
      acc[r][0] = bb0.x; acc[r][1] = bb0.y; acc[r][2] = bb0.z; acc[r][3] = bb0.w;
      acc[r][4] = bb1.x; acc[r][5] = bb1.y; acc[r][6] = bb1.z; acc[r][7] = bb1.w;
    }
    for (int i = 0; i < 64; ++i) {
      float fa[4];
#pragma unroll
      for (int r = 0; r < 4; ++r) fa[r] = h2[k0 + r][i];
      const float4 w0 = *(const float4*)(W3 + i * 128 + j0);
      const float4 w1 = *(const float4*)(W3 + i * 128 + j0 + 4);
#pragma unroll
      for (int r = 0; r < 4; ++r) {
        acc[r][0] += fa[r] * w0.x; acc[r][1] += fa[r] * w0.y;
        acc[r][2] += fa[r] * w0.z; acc[r][3] += fa[r] * w0.w;
        acc[r][4] += fa[r] * w1.x; acc[r][5] += fa[r] * w1.y;
        acc[r][6] += fa[r] * w1.z; acc[r][7] += fa[r] * w1.w;
      }
    }
    float vmax[8];
#pragma unroll
    for (int q = 0; q < 8; ++q) vmax[q] = -INFINITY;
#pragma unroll
    for (int r = 0; r < 4; ++r) {
      if (valid_s[k0 + r]) {
#pragma unroll
        for (int q = 0; q < 8; ++q) vmax[q] = fmaxf(vmax[q], acc[r][q]);
      }
    }
    float4 v0, v1;
    v0.x = vmax[0]; v0.y = vmax[1]; v0.z = vmax[2]; v0.w = vmax[3];
    v1.x = vmax[4]; v1.y = vmax[5]; v1.z = vmax[6]; v1.w = vmax[7];
    *(float4*)(&red[tr][j0]) = v0;
    *(float4*)(&red[tr][j0 + 4]) = v1;
  }
  __syncthreads();

  if (t < 128) {
    float m = red[0][t];
#pragma unroll
    for (int r = 1; r < 16; ++r) m = fmaxf(m, red[r][t]);
    out[(size_t)c * 128 + t] = m;
  }
}

extern "C" void kernel_launch(void* const* d_in, const int* in_sizes, int n_in,
                              void* d_out, int out_size, void* d_ws, size_t ws_size,
                              hipStream_t stream) {
  const float* x   = (const float*)d_in[0];
  const float* pos = (const float*)d_in[1];
  // d_in[2] = batch (unused; layout is implicit)
  const float* W1 = (const float*)d_in[3];
  const float* b1 = (const float*)d_in[4];
  const float* W2 = (const float*)d_in[5];
  const float* b2 = (const float*)d_in[6];
  const float* W3 = (const float*)d_in[7];
  const float* b3 = (const float*)d_in[8];

  // workspace layout
  int* fps_idx   = (int*)d_ws;                    // 16384 ints
  int* nbr       = fps_idx + (NB * SS);           // 16384*64 ints
  float* centers = (float*)(nbr + (size_t)NB * SS * KK);  // 16384*3 floats

  // output layout: x_out [16384,128] | pos_out [16384,3] | batch_out [16384]
  float* out_x     = (float*)d_out;
  float* out_pos   = out_x + (size_t)NB * SS * 128;
  float* out_batch = out_pos + (size_t)NB * SS * 3;

  fps_kernel<<<NB, FPS_TPB, 0, stream>>>(pos, fps_idx, centers, out_pos, out_batch);
  ballq_kernel<<<NB * SS, 256, 0, stream>>>(pos, centers, nbr);
  mlp_kernel<<<NB * SS, 256, 0, stream>>>(x, pos, centers, nbr,
                                          W1, b1, W2, b2, W3, b3, out_x);
}

// Round 2
// 1744.756 us; speedup vs baseline: 1.9096x; 1.9096x over previous
//
#include <hip/hip_runtime.h>
#include <math.h>

#define NB   16
#define NPTS 4096
#define SS   1024
#define KK   64
#define CIN  64

// d2 computed to bit-match XLA: separate mul/add (no FMA contraction),
// sum order (dx^2 + dy^2) + dz^2.
__device__ __forceinline__ float dist2(float ax, float ay, float az,
                                       float bx, float by, float bz) {
#pragma clang fp contract(off)
  float dx = ax - bx, dy = ay - by, dz = az - bz;
  float a = dx * dx, b = dy * dy, c = dz * dz;
  return (a + b) + c;
}

// DPP max-reduce step: v = max(v, dpp_move(v, ctrl)); invalid lanes keep old v.
#define DPPMAX(v, ctrl, rmask)                                                 \
  fmaxf((v), __int_as_float(__builtin_amdgcn_update_dpp(                       \
                 __float_as_int(v), __float_as_int(v), (ctrl), (rmask), 0xf,   \
                 false)))

// ---------------------------------------------------------------------------
// Kernel 1: farthest point sampling, one block of 1024 per cloud.
// Exact reference semantics: start at point 0, S-1 iterations of
// argmax(dmin) (first-index tie-break) then dmin = min(dmin, d2(new)).
// Argmax: per-thread best (4 pts) -> wave DPP max + ballot (first lane =
// lowest index) -> 16 packed u64 wave results in LDS, one barrier/iter.
// ---------------------------------------------------------------------------
#define FPS_TPB 1024
#define FPS_PPT 4

__global__ __launch_bounds__(FPS_TPB) void fps_kernel(
    const float* __restrict__ pos, float* __restrict__ centers,
    float* __restrict__ out_pos, float* __restrict__ out_batch) {
  __shared__ float px[NPTS], py[NPTS], pz[NPTS];
  __shared__ unsigned long long swk[2][16];

  const int b = blockIdx.x, t = threadIdx.x;
  const float* p = pos + (size_t)b * NPTS * 3;

  // stage positions (coalesced linear read, SoA in LDS)
  for (int j = t; j < NPTS * 3; j += FPS_TPB) {
    float v = p[j];
    int pt = j / 3, ch = j - pt * 3;
    if (ch == 0) px[pt] = v;
    else if (ch == 1) py[pt] = v;
    else pz[pt] = v;
  }
  out_batch[b * SS + t] = (float)b;  // SS == FPS_TPB
  __syncthreads();

  const int base = t * FPS_PPT;
  float x[FPS_PPT], y[FPS_PPT], z[FPS_PPT], dm[FPS_PPT];
  const float c0x = px[0], c0y = py[0], c0z = pz[0];
#pragma unroll
  for (int u = 0; u < FPS_PPT; ++u) {
    x[u] = px[base + u]; y[u] = py[base + u]; z[u] = pz[base + u];
    dm[u] = dist2(x[u], y[u], z[u], c0x, c0y, c0z);
  }
  if (t == 0) {
    int r = b * SS;
    centers[r * 3 + 0] = c0x; centers[r * 3 + 1] = c0y; centers[r * 3 + 2] = c0z;
    out_pos[r * 3 + 0] = c0x; out_pos[r * 3 + 1] = c0y; out_pos[r * 3 + 2] = c0z;
  }

  // per-thread running best (strict > keeps lowest local index)
  float bv = dm[0]; int bi = base;
#pragma unroll
  for (int u = 1; u < FPS_PPT; ++u)
    if (dm[u] > bv) { bv = dm[u]; bi = base + u; }

  const int wid = t >> 6, lane = t & 63;
  int parity = 0;
  for (int s = 1; s < SS; ++s) {
    // wave max of bv via DPP (result in lane 63)
    float wv = bv;
    wv = DPPMAX(wv, 0x111, 0xf);  // row_shr:1
    wv = DPPMAX(wv, 0x112, 0xf);  // row_shr:2
    wv = DPPMAX(wv, 0x114, 0xf);  // row_shr:4
    wv = DPPMAX(wv, 0x118, 0xf);  // row_shr:8
    wv = DPPMAX(wv, 0x142, 0xa);  // row_bcast:15 -> rows 1,3
    wv = DPPMAX(wv, 0x143, 0xc);  // row_bcast:31 -> rows 2,3
    const float gvw = __int_as_float(__builtin_amdgcn_readlane(__float_as_int(wv), 63));
    // first lane holding the max = lowest point index in this wave
    unsigned long long mk = __ballot(bv == gvw);
    int fl = __ffsll((long long)mk) - 1;
    int giw = __builtin_amdgcn_readlane(bi, fl);
    if (lane == 0)
      swk[parity][wid] = ((unsigned long long)__float_as_uint(gvw) << 32) |
                         (unsigned)(~(unsigned)giw);
    __syncthreads();
    // all threads reduce the 16 wave keys identically (max key = max d2, min idx)
    unsigned long long bk = swk[parity][0];
#pragma unroll
    for (int w = 1; w < 16; ++w) {
      unsigned long long ok = swk[parity][w];
      if (ok > bk) bk = ok;
    }
    const int gi = (int)(~(unsigned)bk);
    const float cx = px[gi], cy = py[gi], cz = pz[gi];
    if (t == 0) {
      int r = b * SS + s;
      centers[r * 3 + 0] = cx; centers[r * 3 + 1] = cy; centers[r * 3 + 2] = cz;
      out_pos[r * 3 + 0] = cx; out_pos[r * 3 + 1] = cy; out_pos[r * 3 + 2] = cz;
    }
    // dmin update, fused with next-iteration local argmax
    dm[0] = fminf(dm[0], dist2(x[0], y[0], z[0], cx, cy, cz));
    bv = dm[0]; bi = base;
#pragma unroll
    for (int u = 1; u < FPS_PPT; ++u) {
      dm[u] = fminf(dm[u], dist2(x[u], y[u], z[u], cx, cy, cz));
      if (dm[u] > bv) { bv = dm[u]; bi = base + u; }
    }
    parity ^= 1;
  }
}

// ---------------------------------------------------------------------------
// Kernel 2: ball query — compact in-radius candidates (d2,idx) into LDS,
// then exact rank by pairwise counting on packed keys (total order via idx
// in the low bits -> no ties; matches lax.top_k lowest-index semantics).
// One block of 256 per center.
// ---------------------------------------------------------------------------
#define BQ_CAP 1024

__global__ __launch_bounds__(256) void ballq_kernel(
    const float* __restrict__ pos, const float* __restrict__ centers,
    int* __restrict__ nbr) {
  __shared__ unsigned long long ckey[BQ_CAP];
  __shared__ int scnt;

  const int c = blockIdx.x, t = threadIdx.x;
  const int b = c >> 10;
  const float R2 = 0.04f;  // f32(0.2**2) — matches XLA's weak-typed compare

  if (t == 0) scnt = 0;
  const float cx = centers[c * 3 + 0], cy = centers[c * 3 + 1], cz = centers[c * 3 + 2];
  const float* p = pos + (size_t)b * NPTS * 3;
  __syncthreads();

  for (int i = t; i < NPTS; i += 256) {
    float ax = p[i * 3 + 0], ay = p[i * 3 + 1], az = p[i * 3 + 2];
    float d2 = dist2(cx, cy, cz, ax, ay, az);
    if (d2 <= R2) {
      int s = atomicAdd(&scnt, 1);
      if (s < BQ_CAP)
        ckey[s] = ((unsigned long long)__float_as_uint(d2) << 32) | (unsigned)i;
    }
  }
  __syncthreads();
  const int nv = min(scnt, BQ_CAP);

  // pad unused neighbor slots (only when fewer than K in-radius)
  if (t >= nv && t < KK) nbr[(size_t)c * KK + t] = -1;

  // exact rank of each candidate among all candidates; keys are unique
  for (int s = t; s < nv; s += 256) {
    unsigned long long k = ckey[s];
    int r = 0;
    for (int j = 0; j < nv; ++j) r += (ckey[j] < k) ? 1 : 0;
    if (r < KK) nbr[(size_t)c * KK + r] = b * NPTS + (int)(k & 0xFFFFFFFFu);
  }
}

// ---------------------------------------------------------------------------
// Kernel 3: gather + 3-layer MLP + masked max-pool, one block per center.
// fp32 vector-ALU, 4x4 register-blocked tiles; weights read from global
// (L1-resident: W1+W2+W3 = 66 KB total, shared by all 16384 blocks).
// ---------------------------------------------------------------------------
__global__ __launch_bounds__(256) void mlp_kernel(
    const float* __restrict__ x, const float* __restrict__ pos,
    const float* __restrict__ centers, const int* __restrict__ nbr,
    const float* __restrict__ W1, const float* __restrict__ b1,
    const float* __restrict__ W2, const float* __restrict__ b2,
    const float* __restrict__ W3, const float* __restrict__ b3,
    float* __restrict__ out) {
  __shared__ float feat[64][68];  // 67 used (64 ch + 3 rel), stride 68
  __shared__ float h1[64][68];
  __shared__ float h2[64][68];
  __shared__ float red[16][128];
  __shared__ int nbr_s[64];
  __shared__ int valid_s[64];

  const int c = blockIdx.x, t = threadIdx.x;

  if (t < 64) {
    int g = nbr[(size_t)c * KK + t];
    nbr_s[t] = g;
    valid_s[t] = (g >= 0) ? 1 : 0;
  }
  __syncthreads();

  // gather x features: row k = neighbor, 64 channels
  {
    const int ch = t & 63;
    for (int k = t >> 6; k < 64; k += 4) {
      int g = nbr_s[k];
      feat[k][ch] = (g >= 0) ? x[(size_t)g * CIN + ch] : 0.f;
    }
  }
  if (t < 64) {
    int g = nbr_s[t];
    float cx = centers[c * 3 + 0], cy = centers[c * 3 + 1], cz = centers[c * 3 + 2];
    if (g >= 0) {
      feat[t][64] = pos[(size_t)g * 3 + 0] - cx;
      feat[t][65] = pos[(size_t)g * 3 + 1] - cy;
      feat[t][66] = pos[(size_t)g * 3 + 2] - cz;
    } else {
      feat[t][64] = 0.f; feat[t][65] = 0.f; feat[t][66] = 0.f;
    }
    feat[t][67] = 0.f;
  }
  __syncthreads();

  const int tr = t >> 4, tc = t & 15;
  const int k0 = tr * 4;

  // Layer 1: relu(feat[64x67] @ W1[67x64] + b1) -> h1
  {
    const int j0 = tc * 4;
    float acc[4][4];
    const float4 bb = *(const float4*)(b1 + j0);
#pragma unroll
    for (int r = 0; r < 4; ++r) {
      acc[r][0] = bb.x; acc[r][1] = bb.y; acc[r][2] = bb.z; acc[r][3] = bb.w;
    }
    for (int i = 0; i < 67; ++i) {
      float fa[4];
#pragma unroll
      for (int r = 0; r < 4; ++r) fa[r] = feat[k0 + r][i];
      const float4 wb = *(const float4*)(W1 + i * 64 + j0);
#pragma unroll
      for (int r = 0; r < 4; ++r) {
        acc[r][0] += fa[r] * wb.x; acc[r][1] += fa[r] * wb.y;
        acc[r][2] += fa[r] * wb.z; acc[r][3] += fa[r] * wb.w;
      }
    }
#pragma unroll
    for (int r = 0; r < 4; ++r) {
      float4 v;
      v.x = fmaxf(acc[r][0], 0.f); v.y = fmaxf(acc[r][1], 0.f);
      v.z = fmaxf(acc[r][2], 0.f); v.w = fmaxf(acc[r][3], 0.f);
      *(float4*)(&h1[k0 + r][j0]) = v;
    }
  }
  __syncthreads();

  // Layer 2: relu(h1[64x64] @ W2[64x64] + b2) -> h2
  {
    const int j0 = tc * 4;
    float acc[4][4];
    const float4 bb = *(const float4*)(b2 + j0);
#pragma unroll
    for (int r = 0; r < 4; ++r) {
      acc[r][0] = bb.x; acc[r][1] = bb.y; acc[r][2] = bb.z; acc[r][3] = bb.w;
    }
    for (int i = 0; i < 64; ++i) {
      float fa[4];
#pragma unroll
      for (int r = 0; r < 4; ++r) fa[r] = h1[k0 + r][i];
      const float4 wb = *(const float4*)(W2 + i * 64 + j0);
#pragma unroll
      for (int r = 0; r < 4; ++r) {
        acc[r][0] += fa[r] * wb.x; acc[r][1] += fa[r] * wb.y;
        acc[r][2] += fa[r] * wb.z; acc[r][3] += fa[r] * wb.w;
      }
    }
#pragma unroll
    for (int r = 0; r < 4; ++r) {
      float4 v;
      v.x = fmaxf(acc[r][0], 0.f); v.y = fmaxf(acc[r][1], 0.f);
      v.z = fmaxf(acc[r][2], 0.f); v.w = fmaxf(acc[r][3], 0.f);
      *(float4*)(&h2[k0 + r][j0]) = v;
    }
  }
  __syncthreads();

  // Layer 3: h2[64x64] @ W3[64x128] + b3, masked max over k
  {
    const int j0 = tc * 8;
    float acc[4][8];
    const float4 bb0 = *(const float4*)(b3 + j0);
    const float4 bb1 = *(const float4*)(b3 + j0 + 4);
#pragma unroll
    for (int r = 0; r < 4; ++r) {
      acc[r][0] = bb0.x; acc[r][1] = bb0.y; acc[r][2] = bb0.z; acc[r][3] = bb0.w;
      acc[r][4] = bb1.x; acc[r][5] = bb1.y; acc[r][6] = bb1.z; acc[r][7] = bb1.w;
    }
    for (int i = 0; i < 64; ++i) {
      float fa[4];
#pragma unroll
      for (int r = 0; r < 4; ++r) fa[r] = h2[k0 + r][i];
      const float4 w0 = *(const float4*)(W3 + i * 128 + j0);
      const float4 w1 = *(const float4*)(W3 + i * 128 + j0 + 4);
#pragma unroll
      for (int r = 0; r < 4; ++r) {
        acc[r][0] += fa[r] * w0.x; acc[r][1] += fa[r] * w0.y;
        acc[r][2] += fa[r] * w0.z; acc[r][3] += fa[r] * w0.w;
        acc[r][4] += fa[r] * w1.x; acc[r][5] += fa[r] * w1.y;
        acc[r][6] += fa[r] * w1.z; acc[r][7] += fa[r] * w1.w;
      }
    }
    float vmax[8];
#pragma unroll
    for (int q = 0; q < 8; ++q) vmax[q] = -INFINITY;
#pragma unroll
    for (int r = 0; r < 4; ++r) {
      if (valid_s[k0 + r]) {
#pragma unroll
        for (int q = 0; q < 8; ++q) vmax[q] = fmaxf(vmax[q], acc[r][q]);
      }
    }
    float4 v0, v1;
    v0.x = vmax[0]; v0.y = vmax[1]; v0.z = vmax[2]; v0.w = vmax[3];
    v1.x = vmax[4]; v1.y = vmax[5]; v1.z = vmax[6]; v1.w = vmax[7];
    *(float4*)(&red[tr][j0]) = v0;
    *(float4*)(&red[tr][j0 + 4]) = v1;
  }
  __syncthreads();

  if (t < 128) {
    float m = red[0][t];
#pragma unroll
    for (int r = 1; r < 16; ++r) m = fmaxf(m, red[r][t]);
    out[(size_t)c * 128 + t] = m;
  }
}

extern "C" void kernel_launch(void* const* d_in, const int* in_sizes, int n_in,
                              void* d_out, int out_size, void* d_ws, size_t ws_size,
                              hipStream_t stream) {
  const float* x   = (const float*)d_in[0];
  const float* pos = (const float*)d_in[1];
  // d_in[2] = batch (unused; layout is implicit)
  const float* W1 = (const float*)d_in[3];
  const float* b1 = (const float*)d_in[4];
  const float* W2 = (const float*)d_in[5];
  const float* b2 = (const float*)d_in[6];
  const float* W3 = (const float*)d_in[7];
  const float* b3 = (const float*)d_in[8];

  // workspace layout
  int* nbr       = (int*)d_ws;                             // 16384*64 ints
  float* centers = (float*)(nbr + (size_t)NB * SS * KK);   // 16384*3 floats

  // output layout: x_out [16384,128] | pos_out [16384,3] | batch_out [16384]
  float* out_x     = (float*)d_out;
  float* out_pos   = out_x + (size_t)NB * SS * 128;
  float* out_batch = out_pos + (size_t)NB * SS * 3;

  fps_kernel<<<NB, FPS_TPB, 0, stream>>>(pos, centers, out_pos, out_batch);
  ballq_kernel<<<NB * SS, 256, 0, stream>>>(pos, centers, nbr);
  mlp_kernel<<<NB * SS, 256, 0, stream>>>(x, pos, centers, nbr,
                                          W1, b1, W2, b2, W3, b3, out_x);
}

// Round 3
// 1053.813 us; speedup vs baseline: 3.1617x; 1.6557x over previous
//
#include <hip/hip_runtime.h>
#include <math.h>

#define NB   16
#define NPTS 4096
#define SS   1024
#define KK   64
#define CIN  64

typedef unsigned short ushort_t;
typedef float vf2 __attribute__((ext_vector_type(2)));
typedef unsigned long long vu2 __attribute__((ext_vector_type(2)));
typedef short bf8v __attribute__((ext_vector_type(8)));
typedef float f4v __attribute__((ext_vector_type(4)));

// d2 computed to bit-match XLA: separate mul/add (no FMA contraction),
// sum order (dx^2 + dy^2) + dz^2.
__device__ __forceinline__ float dist2(float ax, float ay, float az,
                                       float bx, float by, float bz) {
#pragma clang fp contract(off)
  float dx = ax - bx, dy = ay - by, dz = az - bz;
  float a = dx * dx, b = dy * dy, c = dz * dz;
  return (a + b) + c;
}

// packed (2-wide) variant — v_pk_mul/add are IEEE-identical to scalar
__device__ __forceinline__ vf2 dist2v(vf2 x, vf2 y, vf2 z,
                                      vf2 cx, vf2 cy, vf2 cz) {
#pragma clang fp contract(off)
  vf2 dx = x - cx, dy = y - cy, dz = z - cz;
  vf2 a = dx * dx, b = dy * dy, c = dz * dz;
  return (a + b) + c;
}

// f32 -> bf16 round-to-nearest-even (finite inputs only)
__device__ __forceinline__ ushort_t f2bf(float f) {
  unsigned u = __float_as_uint(f);
  return (ushort_t)((u + 0x7FFFu + ((u >> 16) & 1u)) >> 16);
}

// DPP max-reduce step: v = max(v, dpp_move(v, ctrl)); invalid lanes keep old v.
#define DPPMAX(v, ctrl, rmask)                                                 \
  fmaxf((v), __int_as_float(__builtin_amdgcn_update_dpp(                       \
                 __float_as_int(v), __float_as_int(v), (ctrl), (rmask), 0xf,   \
                 false)))

// ---------------------------------------------------------------------------
// Kernel 1: farthest point sampling, one block of 512 per cloud.
// Exact reference semantics: start at point 0, S-1 iterations of
// argmax(dmin) (first-index tie-break) then dmin = min(dmin, d2(new)).
// VALU-minimized: pk-f32 update, fmax-only tracking (index recovered via
// ballot), 8 cross-wave keys reduced with 7 u64 compares.
// ---------------------------------------------------------------------------
#define FPS_TPB 512
#define FPS_PPT 8   // points per thread
#define FPS_NW  8   // waves per block

__global__ __launch_bounds__(FPS_TPB) void fps_kernel(
    const float* __restrict__ pos, float* __restrict__ centers,
    float* __restrict__ out_pos, float* __restrict__ out_batch) {
  __shared__ float px[NPTS], py[NPTS], pz[NPTS];
  __shared__ __align__(16) unsigned long long swk[2][FPS_NW];

  const int b = blockIdx.x, t = threadIdx.x;
  const float* p = pos + (size_t)b * NPTS * 3;

  // stage positions (coalesced linear read, SoA in LDS)
  for (int j = t; j < NPTS * 3; j += FPS_TPB) {
    float v = p[j];
    int pt = j / 3, ch = j - pt * 3;
    if (ch == 0) px[pt] = v;
    else if (ch == 1) py[pt] = v;
    else pz[pt] = v;
  }
  for (int j = t; j < SS; j += FPS_TPB) out_batch[b * SS + j] = (float)b;
  __syncthreads();

  const int base = t * FPS_PPT;
  vf2 x2[4], y2[4], z2[4], dm2[4];
  const float c0x = px[0], c0y = py[0], c0z = pz[0];
  {
    vf2 cX = {c0x, c0x}, cY = {c0y, c0y}, cZ = {c0z, c0z};
#pragma unroll
    for (int u = 0; u < 4; ++u) {
      x2[u].x = px[base + 2 * u]; x2[u].y = px[base + 2 * u + 1];
      y2[u].x = py[base + 2 * u]; y2[u].y = py[base + 2 * u + 1];
      z2[u].x = pz[base + 2 * u]; z2[u].y = pz[base + 2 * u + 1];
      dm2[u] = dist2v(x2[u], y2[u], z2[u], cX, cY, cZ);
    }
  }
  if (t == 0) {
    int r = b * SS;
    centers[r * 3 + 0] = c0x; centers[r * 3 + 1] = c0y; centers[r * 3 + 2] = c0z;
    out_pos[r * 3 + 0] = c0x; out_pos[r * 3 + 1] = c0y; out_pos[r * 3 + 2] = c0z;
  }

  const int lane = t & 63;
  int parity = 0;
  for (int s = 1; s < SS; ++s) {
    // per-thread max of 8 dmin values (value only)
    vf2 m01 = __builtin_elementwise_max(dm2[0], dm2[1]);
    vf2 m23 = __builtin_elementwise_max(dm2[2], dm2[3]);
    vf2 mm = __builtin_elementwise_max(m01, m23);
    float bv = fmaxf(mm.x, mm.y);
    // wave max via DPP (valid result in lane 63)
    float wv = bv;
    wv = DPPMAX(wv, 0x111, 0xf);  // row_shr:1
    wv = DPPMAX(wv, 0x112, 0xf);  // row_shr:2
    wv = DPPMAX(wv, 0x114, 0xf);  // row_shr:4
    wv = DPPMAX(wv, 0x118, 0xf);  // row_shr:8
    wv = DPPMAX(wv, 0x142, 0xa);  // row_bcast:15 -> rows 1,3
    wv = DPPMAX(wv, 0x143, 0xc);  // row_bcast:31 -> rows 2,3
    const float gvw =
        __int_as_float(__builtin_amdgcn_readlane(__float_as_int(wv), 63));
    // first lane holding the max = lowest point index in this wave
    unsigned long long mk = __ballot(bv == gvw);
    int fl = __ffsll((long long)mk) - 1;
    // lowest local u with dm == gvw (descending scan keeps first)
    int li = -1;
    if (dm2[3].y == gvw) li = 7;
    if (dm2[3].x == gvw) li = 6;
    if (dm2[2].y == gvw) li = 5;
    if (dm2[2].x == gvw) li = 4;
    if (dm2[1].y == gvw) li = 3;
    if (dm2[1].x == gvw) li = 2;
    if (dm2[0].y == gvw) li = 1;
    if (dm2[0].x == gvw) li = 0;
    if (lane == fl) {
      int gi = base + li;
      swk[parity][t >> 6] =
          ((unsigned long long)__float_as_uint(gvw) << 32) |
          (unsigned)(~(unsigned)gi);
    }
    __syncthreads();
    // reduce 8 wave keys (broadcast reads, 7 u64 compares)
    const vu2* sp = (const vu2*)(&swk[parity][0]);
    vu2 q0 = sp[0], q1 = sp[1], q2 = sp[2], q3 = sp[3];
    unsigned long long bk = q0.x;
    bk = (q0.y > bk) ? q0.y : bk;
    bk = (q1.x > bk) ? q1.x : bk;
    bk = (q1.y > bk) ? q1.y : bk;
    bk = (q2.x > bk) ? q2.x : bk;
    bk = (q2.y > bk) ? q2.y : bk;
    bk = (q3.x > bk) ? q3.x : bk;
    bk = (q3.y > bk) ? q3.y : bk;
    const int gi = (int)(~(unsigned)bk);
    const float cx = px[gi], cy = py[gi], cz = pz[gi];
    if (t == 0) {
      int r = b * SS + s;
      centers[r * 3 + 0] = cx; centers[r * 3 + 1] = cy; centers[r * 3 + 2] = cz;
      out_pos[r * 3 + 0] = cx; out_pos[r * 3 + 1] = cy; out_pos[r * 3 + 2] = cz;
    }
    {
      vf2 cX = {cx, cx}, cY = {cy, cy}, cZ = {cz, cz};
#pragma unroll
      for (int u = 0; u < 4; ++u) {
        vf2 d2 = dist2v(x2[u], y2[u], z2[u], cX, cY, cZ);
        dm2[u] = __builtin_elementwise_min(dm2[u], d2);
      }
    }
    parity ^= 1;
  }
}

// ---------------------------------------------------------------------------
// Kernel 2: ball query — compact in-radius candidates (d2,idx) into LDS,
// then exact rank by pairwise counting on packed keys (total order via idx
// in the low bits -> no ties; matches lax.top_k lowest-index semantics).
// One block of 256 per center.
// ---------------------------------------------------------------------------
#define BQ_CAP 1024

__global__ __launch_bounds__(256) void ballq_kernel(
    const float* __restrict__ pos, const float* __restrict__ centers,
    int* __restrict__ nbr) {
  __shared__ unsigned long long ckey[BQ_CAP];
  __shared__ int scnt;

  const int c = blockIdx.x, t = threadIdx.x;
  const int b = c >> 10;
  const float R2 = 0.04f;  // f32(0.2**2) — matches XLA's weak-typed compare

  if (t == 0) scnt = 0;
  const float cx = centers[c * 3 + 0], cy = centers[c * 3 + 1], cz = centers[c * 3 + 2];
  const float* p = pos + (size_t)b * NPTS * 3;
  __syncthreads();

  for (int i = t; i < NPTS; i += 256) {
    float ax = p[i * 3 + 0], ay = p[i * 3 + 1], az = p[i * 3 + 2];
    float d2 = dist2(cx, cy, cz, ax, ay, az);
    if (d2 <= R2) {
      int s = atomicAdd(&scnt, 1);
      if (s < BQ_CAP)
        ckey[s] = ((unsigned long long)__float_as_uint(d2) << 32) | (unsigned)i;
    }
  }
  __syncthreads();
  const int nv = min(scnt, BQ_CAP);

  // pad unused neighbor slots (only when fewer than K in-radius)
  if (t >= nv && t < KK) nbr[(size_t)c * KK + t] = -1;

  // exact rank of each candidate among all candidates; keys are unique
  for (int s = t; s < nv; s += 256) {
    unsigned long long k = ckey[s];
    int r = 0;
    for (int j = 0; j < nv; ++j) r += (ckey[j] < k) ? 1 : 0;
    if (r < KK) nbr[(size_t)c * KK + r] = b * NPTS + (int)(k & 0xFFFFFFFFu);
  }
}

// ---------------------------------------------------------------------------
// Kernel 2.5: weight prep — transpose + bf16-convert + K-pad the MLP weights
// into workspace once per launch. Layout (ushort elements):
//   [0,6656):      W1T [64 n][104]  (k<67 valid, 67..95 zeroed, 96..103 pad)
//   [6656,11264):  W2T [64 n][72]   (k<64 valid)
//   [11264,20480): W3T [128 n][72]  (k<64 valid)
// ---------------------------------------------------------------------------
#define WPREP_N 20480

__global__ __launch_bounds__(256) void wprep_kernel(
    const float* __restrict__ W1, const float* __restrict__ W2,
    const float* __restrict__ W3, ushort_t* __restrict__ wbuf) {
  int i = blockIdx.x * 256 + threadIdx.x;
  if (i >= WPREP_N) return;
  float v;
  if (i < 6656) {
    int n = i / 104, k = i - n * 104;
    v = (k < 67) ? W1[k * 64 + n] : 0.f;
  } else if (i < 11264) {
    int j = i - 6656;
    int n = j / 72, k = j - n * 72;
    v = (k < 64) ? W2[k * 64 + n] : 0.f;
  } else {
    int j = i - 11264;
    int n = j / 72, k = j - n * 72;
    v = (k < 64) ? W3[k * 128 + n] : 0.f;
  }
  wbuf[i] = f2bf(v);
}

// ---------------------------------------------------------------------------
// Kernel 3: gather + 3-layer MLP (bf16 MFMA, fp32 accum/bias/relu) + masked
// max-pool. One block of 256 (4 waves) per center; wave w owns row-block
// m in [16w,16w+16). mfma_f32_16x16x32_bf16:
//   A-frag: A[m=lane&15][k=quad*8+j]; B-frag: B[k=quad*8+j][n=lane&15]
//   C/D:    D[m=quad*4+r][n=lane&15]         (learn_hip m89/m91 verified)
// ---------------------------------------------------------------------------
__global__ __launch_bounds__(256) void mlp_kernel(
    const float* __restrict__ x, const float* __restrict__ pos,
    const float* __restrict__ centers, const int* __restrict__ nbr,
    const ushort_t* __restrict__ wbuf,
    const float* __restrict__ b1, const float* __restrict__ b2,
    const float* __restrict__ b3, float* __restrict__ out) {
  __shared__ ushort_t wl[WPREP_N];       // staged weights (see wprep layout)
  __shared__ ushort_t feat[64][104];     // k: 0..66 data, 67..95 zero
  __shared__ ushort_t h1[64][72];
  __shared__ ushort_t h2[64][72];
  __shared__ float red[4][128];
  __shared__ int nbr_s[64];
  __shared__ int valid_s[64];

  const int c = blockIdx.x, t = threadIdx.x;

  // stage weights: 2560 float4s, 10 per thread
  {
    const float4* src = (const float4*)wbuf;
    float4* dst = (float4*)wl;
#pragma unroll
    for (int i = 0; i < 10; ++i) dst[t + 256 * i] = src[t + 256 * i];
  }
  if (t < 64) {
    int g = nbr[(size_t)c * KK + t];
    nbr_s[t] = g;
    valid_s[t] = (g >= 0) ? 1 : 0;
  }
  __syncthreads();

  // gather x features -> bf16 (2 channels/thread, 8 rows/thread)
  {
    const int c2 = t & 31;
    for (int k = t >> 5; k < 64; k += 8) {
      int g = nbr_s[k];
      float vx = 0.f, vy = 0.f;
      if (g >= 0) {
        const float* xp = x + (size_t)g * CIN + 2 * c2;
        vx = xp[0]; vy = xp[1];
      }
      unsigned pk = ((unsigned)f2bf(vy) << 16) | (unsigned)f2bf(vx);
      *(unsigned*)&feat[k][2 * c2] = pk;
    }
  }
  // zero pad k = 68..95
  for (int i = t; i < 64 * 14; i += 256) {
    int r = i / 14, cp = i - r * 14;
    *(unsigned*)&feat[r][68 + 2 * cp] = 0;
  }
  // rel pos (k=64..66) + zero k=67
  if (t < 64) {
    int g = nbr_s[t];
    float cx = centers[c * 3 + 0], cy = centers[c * 3 + 1], cz = centers[c * 3 + 2];
    float rx = 0.f, ry = 0.f, rz = 0.f;
    if (g >= 0) {
      rx = pos[(size_t)g * 3 + 0] - cx;
      ry = pos[(size_t)g * 3 + 1] - cy;
      rz = pos[(size_t)g * 3 + 2] - cz;
    }
    feat[t][64] = f2bf(rx); feat[t][65] = f2bf(ry); feat[t][66] = f2bf(rz);
    feat[t][67] = 0;
  }
  __syncthreads();

  const int w = t >> 6, lane = t & 63, lr = lane & 15, quad = lane >> 4;
  const int mrow = (w << 4) + lr;         // A row for this lane
  const int mout = (w << 4) + (quad << 2); // first C row for this lane

  // Layer 1: relu(feat[64x96] @ W1T + b1) -> h1 bf16   (K=96: 3 steps)
  {
    f4v acc[4] = {{0,0,0,0},{0,0,0,0},{0,0,0,0},{0,0,0,0}};
#pragma unroll
    for (int kb = 0; kb < 3; ++kb) {
      const int ko = kb * 32 + quad * 8;
      bf8v a = *(const bf8v*)&feat[mrow][ko];
#pragma unroll
      for (int nb = 0; nb < 4; ++nb) {
        bf8v bb = *(const bf8v*)&wl[(nb * 16 + lr) * 104 + ko];
        acc[nb] = __builtin_amdgcn_mfma_f32_16x16x32_bf16(a, bb, acc[nb], 0, 0, 0);
      }
    }
#pragma unroll
    for (int nb = 0; nb < 4; ++nb) {
      const int n = nb * 16 + lr;
      const float bias = b1[n];
#pragma unroll
      for (int r = 0; r < 4; ++r)
        h1[mout + r][n] = f2bf(fmaxf(acc[nb][r] + bias, 0.f));
    }
  }
  __syncthreads();

  // Layer 2: relu(h1[64x64] @ W2T + b2) -> h2 bf16   (K=64: 2 steps)
  {
    f4v acc[4] = {{0,0,0,0},{0,0,0,0},{0,0,0,0},{0,0,0,0}};
#pragma unroll
    for (int kb = 0; kb < 2; ++kb) {
      const int ko = kb * 32 + quad * 8;
      bf8v a = *(const bf8v*)&h1[mrow][ko];
#pragma unroll
      for (int nb = 0; nb < 4; ++nb) {
        bf8v bb = *(const bf8v*)&wl[6656 + (nb * 16 + lr) * 72 + ko];
        acc[nb] = __builtin_amdgcn_mfma_f32_16x16x32_bf16(a, bb, acc[nb], 0, 0, 0);
      }
    }
#pragma unroll
    for (int nb = 0; nb < 4; ++nb) {
      const int n = nb * 16 + lr;
      const float bias = b2[n];
#pragma unroll
      for (int r = 0; r < 4; ++r)
        h2[mout + r][n] = f2bf(fmaxf(acc[nb][r] + bias, 0.f));
    }
  }
  __syncthreads();

  // Layer 3: h2[64x64] @ W3T, masked max over rows, + b3 at the end
  {
    f4v acc[8] = {{0,0,0,0},{0,0,0,0},{0,0,0,0},{0,0,0,0},
                  {0,0,0,0},{0,0,0,0},{0,0,0,0},{0,0,0,0}};
#pragma unroll
    for (int kb = 0; kb < 2; ++kb) {
      const int ko = kb * 32 + quad * 8;
      bf8v a = *(const bf8v*)&h2[mrow][ko];
#pragma unroll
      for (int nb = 0; nb < 8; ++nb) {
        bf8v bb = *(const bf8v*)&wl[11264 + (nb * 16 + lr) * 72 + ko];
        acc[nb] = __builtin_amdgcn_mfma_f32_16x16x32_bf16(a, bb, acc[nb], 0, 0, 0);
      }
    }
    float vmax[8];
#pragma unroll
    for (int nb = 0; nb < 8; ++nb) vmax[nb] = -INFINITY;
#pragma unroll
    for (int r = 0; r < 4; ++r) {
      if (valid_s[mout + r]) {
#pragma unroll
        for (int nb = 0; nb < 8; ++nb) vmax[nb] = fmaxf(vmax[nb], acc[nb][r]);
      }
    }
#pragma unroll
    for (int nb = 0; nb < 8; ++nb) {
      float v = vmax[nb];
      v = fmaxf(v, __shfl_xor(v, 16));
      v = fmaxf(v, __shfl_xor(v, 32));
      if (quad == 0) red[w][nb * 16 + lr] = v;
    }
  }
  __syncthreads();

  if (t < 128) {
    float m = fmaxf(fmaxf(red[0][t], red[1][t]), fmaxf(red[2][t], red[3][t]));
    out[(size_t)c * 128 + t] = m + b3[t];
  }
}

extern "C" void kernel_launch(void* const* d_in, const int* in_sizes, int n_in,
                              void* d_out, int out_size, void* d_ws, size_t ws_size,
                              hipStream_t stream) {
  const float* x   = (const float*)d_in[0];
  const float* pos = (const float*)d_in[1];
  // d_in[2] = batch (unused; layout is implicit)
  const float* W1 = (const float*)d_in[3];
  const float* b1 = (const float*)d_in[4];
  const float* W2 = (const float*)d_in[5];
  const float* b2 = (const float*)d_in[6];
  const float* W3 = (const float*)d_in[7];
  const float* b3 = (const float*)d_in[8];

  // workspace layout
  int* nbr       = (int*)d_ws;                             // 16384*64 ints
  float* centers = (float*)(nbr + (size_t)NB * SS * KK);   // 16384*3 floats
  ushort_t* wbuf = (ushort_t*)(centers + (size_t)NB * SS * 3);  // 20480 bf16

  // output layout: x_out [16384,128] | pos_out [16384,3] | batch_out [16384]
  float* out_x     = (float*)d_out;
  float* out_pos   = out_x + (size_t)NB * SS * 128;
  float* out_batch = out_pos + (size_t)NB * SS * 3;

  wprep_kernel<<<(WPREP_N + 255) / 256, 256, 0, stream>>>(W1, W2, W3, wbuf);
  fps_kernel<<<NB, FPS_TPB, 0, stream>>>(pos, centers, out_pos, out_batch);
  ballq_kernel<<<NB * SS, 256, 0, stream>>>(pos, centers, nbr);
  mlp_kernel<<<NB * SS, 256, 0, stream>>>(x, pos, centers, nbr, wbuf,
                                          b1, b2, b3, out_x);
}